// Round 1
// baseline (544.811 us; speedup 1.0000x reference)
//
#include <hip/hip_runtime.h>

// BlockMaskGenerator: B=8192, NUM_BLOCKS=4, H=W=64, S=4096.
// Outputs (int32, concatenated): context[B*S], target[B*S], positions[B*S], counts[B].
// positions[b] = stable partition: target indices ascending, then non-target ascending.

#define NBLK 4
#define HGT 64
#define WID 64
#define SEQ 4096

__global__ __launch_bounds__(256) void blockmask_kernel(
    const float* __restrict__ scales,
    const float* __restrict__ rand_tops,
    const float* __restrict__ rand_lefts,
    int* __restrict__ out,
    int B)
{
    const int b   = blockIdx.x;
    const int tid = threadIdx.x;

    // --- per-batch rectangles (computed redundantly by all threads; trivial) ---
    int top[NBLK], bot[NBLK], lft[NBLK], rgt[NBLK];
#pragma unroll
    for (int j = 0; j < NBLK; ++j) {
        int t = b * NBLK + j;
        float sc = scales[t];
        // s = 0.15 + sc*0.05 in exact fp32 (no FMA contraction)
        float s = __fadd_rn(0.15f, __fmul_rn(sc, 0.05f));
        int area = (int)__fmul_rn(__fmul_rn(s, 64.0f), 64.0f);       // trunc
        int bh = (int)__fsqrt_rn((float)area);                        // IEEE sqrt, trunc
        bh = min(max(bh, 1), HGT);
        int bw = (int)__fdiv_rn((float)area, (float)bh);              // IEEE div, trunc
        bw = min(max(bw, 1), WID);
        int maxt = max(HGT - bh + 1, 1);
        int maxl = max(WID - bw + 1, 1);
        int tp = (int)__fmul_rn(rand_tops[t],  (float)maxt);
        int lf = (int)__fmul_rn(rand_lefts[t], (float)maxl);
        top[j] = tp; bot[j] = tp + bh;
        lft[j] = lf; rgt[j] = lf + bw;
    }

    // --- each thread owns 16 consecutive positions: row r, cols [c0, c0+16) ---
    const int p0 = tid * 16;
    const int r  = p0 >> 6;       // 64 cols per row, 16 | 64 so strip stays in one row
    const int c0 = p0 & 63;

    unsigned mask16 = 0;
#pragma unroll
    for (int j = 0; j < NBLK; ++j) {
        if (r >= top[j] && r < bot[j]) {
            int lo = max(lft[j] - c0, 0);
            int hi = min(rgt[j] - c0, 16);
            if (hi > lo) {
                unsigned m = ((1u << (hi - lo)) - 1u) << lo;
                mask16 |= m;
            }
        }
    }
    int cnt = __popc(mask16);

    // --- block-wide exclusive scan of cnt over 256 threads (wave=64) ---
    const int lane = tid & 63;
    const int wid  = tid >> 6;
    int v = cnt;
#pragma unroll
    for (int d = 1; d < 64; d <<= 1) {
        int t = __shfl_up(v, d, 64);
        if (lane >= d) v += t;
    }
    __shared__ int wsum[4];
    if (lane == 63) wsum[wid] = v;
    __syncthreads();
    int waveOff = 0, total = 0;
#pragma unroll
    for (int w = 0; w < 4; ++w) {
        int ws = wsum[w];
        if (w < wid) waveOff += ws;
        total += ws;
    }
    const int base_t = waveOff + (v - cnt);   // # targets before p0

    // --- masks: int4 vectorized stores (coalesced) ---
    const size_t BS = (size_t)B * SEQ;
    const size_t mbase = (size_t)b * SEQ + (size_t)p0;
    int4* ctx = (int4*)out;
    int4* tgt = (int4*)(out + BS);
    size_t vbase = mbase >> 2;
#pragma unroll
    for (int g = 0; g < 4; ++g) {
        int m = (int)((mask16 >> (g * 4)) & 0xFu);
        int4 tv, cv;
        tv.x =  m       & 1; tv.y = (m >> 1) & 1; tv.z = (m >> 2) & 1; tv.w = (m >> 3) & 1;
        cv.x = 1 - tv.x; cv.y = 1 - tv.y; cv.z = 1 - tv.z; cv.w = 1 - tv.w;
        tgt[vbase + g] = tv;
        ctx[vbase + g] = cv;
    }

    // --- positions: stable partition; two contiguous runs per thread ---
    int* pos = out + 2 * BS + (size_t)b * SEQ;
    int bt = base_t;
    int bn = total + (p0 - base_t);   // non-targets before p0 = p0 - base_t
#pragma unroll
    for (int k = 0; k < 16; ++k) {
        int p = p0 + k;
        if ((mask16 >> k) & 1u) pos[bt++] = p;
        else                    pos[bn++] = p;
    }

    if (tid == 0) out[3 * BS + (size_t)b] = total;
}

extern "C" void kernel_launch(void* const* d_in, const int* in_sizes, int n_in,
                              void* d_out, int out_size, void* d_ws, size_t ws_size,
                              hipStream_t stream) {
    const float* scales     = (const float*)d_in[0];
    const float* rand_tops  = (const float*)d_in[1];
    const float* rand_lefts = (const float*)d_in[2];
    int* out = (int*)d_out;
    int B = in_sizes[0] / NBLK;   // 32768/4 = 8192
    blockmask_kernel<<<B, 256, 0, stream>>>(scales, rand_tops, rand_lefts, out, B);
}

// Round 2
// 402.294 us; speedup vs baseline: 1.3543x; 1.3543x over previous
//
#include <hip/hip_runtime.h>

// BlockMaskGenerator: B=8192, NUM_BLOCKS=4, H=W=64, S=4096.
// Outputs (int32, concatenated): context[B*S], target[B*S], positions[B*S], counts[B].
// positions[b] = stable partition: target indices ascending, then non-target ascending.
//
// Strategy: one 256-thread block per batch row.
//  - Scan ownership: thread owns 16 consecutive positions (one 16-col strip),
//    wave-shuffle + LDS scan gives each thread its target/non-target ranks.
//  - Positions are scattered into LDS (cheap, ~69 TB/s), then streamed out
//    with coalesced int4 stores.
//  - Mask stores use a separate coalesced ownership: store g writes int4 at
//    g*256+tid (consecutive lanes -> contiguous 16B), membership recomputed
//    arithmetically for the 4-wide strip.

#define NBLK 4
#define HGT 64
#define WID 64
#define SEQ 4096

__global__ __launch_bounds__(256) void blockmask_kernel(
    const float* __restrict__ scales,
    const float* __restrict__ rand_tops,
    const float* __restrict__ rand_lefts,
    int* __restrict__ out,
    int B)
{
    __shared__ int pos_s[SEQ];   // 16 KB
    __shared__ int wsum[4];

    const int b   = blockIdx.x;
    const int tid = threadIdx.x;

    // --- per-batch rectangles (computed redundantly by all threads) ---
    int top[NBLK], bot[NBLK], lft[NBLK], rgt[NBLK];
#pragma unroll
    for (int j = 0; j < NBLK; ++j) {
        int t = b * NBLK + j;
        float sc = scales[t];
        float s = __fadd_rn(0.15f, __fmul_rn(sc, 0.05f));           // no FMA contraction
        int area = (int)__fmul_rn(__fmul_rn(s, 64.0f), 64.0f);      // trunc
        int bh = (int)__fsqrt_rn((float)area);                       // IEEE sqrt, trunc
        bh = min(max(bh, 1), HGT);
        int bw = (int)__fdiv_rn((float)area, (float)bh);             // IEEE div, trunc
        bw = min(max(bw, 1), WID);
        int maxt = max(HGT - bh + 1, 1);
        int maxl = max(WID - bw + 1, 1);
        int tp = (int)__fmul_rn(rand_tops[t],  (float)maxt);
        int lf = (int)__fmul_rn(rand_lefts[t], (float)maxl);
        top[j] = tp; bot[j] = tp + bh;
        lft[j] = lf; rgt[j] = lf + bw;
    }

    // --- scan ownership: 16 consecutive positions (row r, cols [c0,c0+16)) ---
    const int p0 = tid * 16;
    const int r  = p0 >> 6;
    const int c0 = p0 & 63;

    unsigned mask16 = 0;
#pragma unroll
    for (int j = 0; j < NBLK; ++j) {
        if (r >= top[j] && r < bot[j]) {
            int lo = max(lft[j] - c0, 0);
            int hi = min(rgt[j] - c0, 16);
            if (hi > lo) mask16 |= ((1u << (hi - lo)) - 1u) << lo;
        }
    }
    const int cnt = __popc(mask16);

    // --- block-wide inclusive scan over 256 threads (wave=64) ---
    const int lane = tid & 63;
    const int wv   = tid >> 6;
    int v = cnt;
#pragma unroll
    for (int d = 1; d < 64; d <<= 1) {
        int t = __shfl_up(v, d, 64);
        if (lane >= d) v += t;
    }
    if (lane == 63) wsum[wv] = v;
    __syncthreads();
    int waveOff = 0, total = 0;
#pragma unroll
    for (int w = 0; w < 4; ++w) {
        int ws = wsum[w];
        if (w < wv) waveOff += ws;
        total += ws;
    }
    const int base_t = waveOff + (v - cnt);   // # targets before p0

    // --- scatter positions into LDS (stable partition) ---
    int bt = base_t;
    int bn = total + (p0 - base_t);
#pragma unroll
    for (int k = 0; k < 16; ++k) {
        int p = p0 + k;
        if ((mask16 >> k) & 1u) pos_s[bt++] = p;
        else                    pos_s[bn++] = p;
    }

    // --- coalesced mask stores (independent ownership: int4 at g*256+tid) ---
    const size_t BS = (size_t)B * SEQ;
    int4* ctx4 = (int4*)out        + (size_t)b * (SEQ / 4);
    int4* tgt4 = (int4*)(out + BS) + (size_t)b * (SEQ / 4);
#pragma unroll
    for (int g = 0; g < 4; ++g) {
        int vidx = g * 256 + tid;
        int p  = vidx * 4;
        int rr = p >> 6;
        int cc = p & 63;
        int m = 0;
#pragma unroll
        for (int j = 0; j < NBLK; ++j) {
            if (rr >= top[j] && rr < bot[j]) {
                int lo = max(lft[j] - cc, 0);
                int hi = min(rgt[j] - cc, 4);
                if (hi > lo) m |= ((1 << (hi - lo)) - 1) << lo;
            }
        }
        int4 tv, cv;
        tv.x =  m       & 1; tv.y = (m >> 1) & 1; tv.z = (m >> 2) & 1; tv.w = (m >> 3) & 1;
        cv.x = tv.x ^ 1;     cv.y = tv.y ^ 1;     cv.z = tv.z ^ 1;     cv.w = tv.w ^ 1;
        tgt4[vidx] = tv;
        ctx4[vidx] = cv;
    }

    // --- stream positions out of LDS, fully coalesced ---
    __syncthreads();
    const int4* ps4 = (const int4*)pos_s;
    int4* pout4 = (int4*)(out + 2 * BS) + (size_t)b * (SEQ / 4);
#pragma unroll
    for (int g = 0; g < 4; ++g) {
        int vidx = g * 256 + tid;
        pout4[vidx] = ps4[vidx];
    }

    if (tid == 0) out[3 * BS + (size_t)b] = total;
}

extern "C" void kernel_launch(void* const* d_in, const int* in_sizes, int n_in,
                              void* d_out, int out_size, void* d_ws, size_t ws_size,
                              hipStream_t stream) {
    const float* scales     = (const float*)d_in[0];
    const float* rand_tops  = (const float*)d_in[1];
    const float* rand_lefts = (const float*)d_in[2];
    int* out = (int*)d_out;
    int B = in_sizes[0] / NBLK;   // 32768/4 = 8192
    blockmask_kernel<<<B, 256, 0, stream>>>(scales, rand_tops, rand_lefts, out, B);
}